// Round 6
// baseline (276.725 us; speedup 1.0000x reference)
//
#include <hip/hip_runtime.h>
#include <hip/hip_fp16.h>
#include <math.h>

#define DEPTH 6
#define NN    128
#define EE    160
#define NF    127
#define DIMM  128
#define INNER 512
#define NNODE 256
#define NBLK  128

typedef _Float16 h2f16 __attribute__((ext_vector_type(2)));

#if defined(__has_builtin)
#if __has_builtin(__builtin_amdgcn_fdot2)
#define HAVE_FDOT2 1
#endif
#endif

__device__ __forceinline__ float fdot2f(h2f16 a, h2f16 b, float c) {
#ifdef HAVE_FDOT2
    return __builtin_amdgcn_fdot2(a, b, c, false);
#else
    return c + (float)a.x * (float)b.x + (float)a.y * (float)b.y;
#endif
}

__device__ __forceinline__ void gload16(const void* g, void* l) {
    __builtin_amdgcn_global_load_lds((const __attribute__((address_space(1))) void*)g,
                                     (__attribute__((address_space(3))) void*)l,
                                     16, 0, 0);
}

// s_waitcnt: vmcnt<=N, exp/lgkm unconstrained. gfx9 encoding:
// vmcnt[3:0]=bits3:0, exp=bits6:4, lgkm=bits11:8, vmcnt[5:4]=bits15:14.
template <int N>
__device__ __forceinline__ void wait_vm() {
    __builtin_amdgcn_s_waitcnt((0xF << 8) | (7 << 4) | (N & 0xF) | ((N >> 4) << 14));
}
__device__ __forceinline__ void wait_lgkm0() { __builtin_amdgcn_s_waitcnt(0xC07F); }
__device__ __forceinline__ void sbar0() { __builtin_amdgcn_sched_barrier(0); }

// 8 KB contiguous half-slice: 8 x (1 KB) DMA calls, linear LDS dest.
__device__ __forceinline__ void stage8c(const char* g, char* lds, int ln) {
#pragma unroll
    for (int i = 0; i < 8; i++)
        gload16(g + i * 1024 + ln * 16, lds + i * 1024);
}
// 8 rows of 1 KB, global row stride rs bytes (f32 staging in k_pre).
__device__ __forceinline__ void stage8f(const char* g, int rs, char* lds, int ln) {
#pragma unroll
    for (int i = 0; i < 8; i++)
        gload16(g + (size_t)i * rs + ln * 16, lds + i * 1024);
}

// ---- dual-node chunked transposed-f16 GEMV units (combine-free) ----
// Weight slab layout (written by k_pre cvt prologue):
//   slice w = 16 KB = 16 chunks x 1 KB; chunk i = K-rows [8i,8i+8) of all 64
//   lane-columns; lane ln's 16 B at chunk + ln*16.
// One weight read from LDS into regs serves BOTH nodes' dot chains.

// C=512, K=128. Lane col = w*64+ln. xA = s_xh[0..128), xB = s_xh[128..256).
template <int NXT>
__device__ __forceinline__ float2 gemv512d(const __half* s_xh, float* wbuf,
                                           const char* nextG, int ln) {
    const char* Wb = (const char*)wbuf;
    float4 wa[8], wb_[8];
    wait_vm<8>();
#pragma unroll
    for (int i = 0; i < 8; i++) wa[i] = *(const float4*)(Wb + i * 1024 + ln * 16);
    sbar0(); wait_lgkm0(); sbar0();
    if (NXT) { stage8c(nextG, (char*)wbuf, ln); wait_vm<8>(); }
    else     wait_vm<0>();
#pragma unroll
    for (int i = 0; i < 8; i++) wb_[i] = *(const float4*)(Wb + 8192 + i * 1024 + ln * 16);
    sbar0(); wait_lgkm0(); sbar0();
    if (NXT) stage8c(nextG + 8192, (char*)wbuf + 8192, ln);
    const float4* XA = (const float4*)s_xh;
    const float4* XB = (const float4*)(s_xh + 128);
    float aA = 0, aB = 0;
#pragma unroll
    for (int i = 0; i < 8; i++) {
        float4 xvA = XA[i], xvB = XB[i];
        const h2f16* wh = (const h2f16*)&wa[i];
        const h2f16* xa = (const h2f16*)&xvA;
        const h2f16* xb = (const h2f16*)&xvB;
        aA = fdot2f(xa[0], wh[0], aA); aA = fdot2f(xa[1], wh[1], aA);
        aA = fdot2f(xa[2], wh[2], aA); aA = fdot2f(xa[3], wh[3], aA);
        aB = fdot2f(xb[0], wh[0], aB); aB = fdot2f(xb[1], wh[1], aB);
        aB = fdot2f(xb[2], wh[2], aB); aB = fdot2f(xb[3], wh[3], aB);
    }
#pragma unroll
    for (int i = 0; i < 8; i++) {
        float4 xvA = XA[8 + i], xvB = XB[8 + i];
        const h2f16* wh = (const h2f16*)&wb_[i];
        const h2f16* xa = (const h2f16*)&xvA;
        const h2f16* xb = (const h2f16*)&xvB;
        aA = fdot2f(xa[0], wh[0], aA); aA = fdot2f(xa[1], wh[1], aA);
        aA = fdot2f(xa[2], wh[2], aA); aA = fdot2f(xa[3], wh[3], aA);
        aB = fdot2f(xb[0], wh[0], aB); aB = fdot2f(xb[1], wh[1], aB);
        aB = fdot2f(xb[2], wh[2], aB); aB = fdot2f(xb[3], wh[3], aB);
    }
    return {aA, aB};
}

// C=128, K=512. Lane: col = w*16+(ln>>2), kq = ln&3 owns rows kq*128+[0,128).
// x kq-padded (4 x 136 halves). Caller combines 4 partials via shfl_xor(1)+(2).
template <int NXT>
__device__ __forceinline__ float2 gemv128d(const __half* xA, const __half* xB,
                                           float* wbuf, const char* nextG, int ln) {
    int kq = ln & 3;
    const char* Wb  = (const char*)wbuf;
    const char* XbA = (const char*)xA + kq * 272;
    const char* XbB = (const char*)xB + kq * 272;
    float4 wa[8], wb_[8];
    wait_vm<8>();
#pragma unroll
    for (int i = 0; i < 8; i++) wa[i] = *(const float4*)(Wb + i * 1024 + ln * 16);
    sbar0(); wait_lgkm0(); sbar0();
    if (NXT) { stage8c(nextG, (char*)wbuf, ln); wait_vm<8>(); }
    else     wait_vm<0>();
#pragma unroll
    for (int i = 0; i < 8; i++) wb_[i] = *(const float4*)(Wb + 8192 + i * 1024 + ln * 16);
    sbar0(); wait_lgkm0(); sbar0();
    if (NXT) stage8c(nextG + 8192, (char*)wbuf + 8192, ln);
    float aA = 0, aB = 0;
#pragma unroll
    for (int i = 0; i < 8; i++) {
        float4 xvA = *(const float4*)(XbA + i * 16);
        float4 xvB = *(const float4*)(XbB + i * 16);
        const h2f16* wh = (const h2f16*)&wa[i];
        const h2f16* xa = (const h2f16*)&xvA;
        const h2f16* xb = (const h2f16*)&xvB;
        aA = fdot2f(xa[0], wh[0], aA); aA = fdot2f(xa[1], wh[1], aA);
        aA = fdot2f(xa[2], wh[2], aA); aA = fdot2f(xa[3], wh[3], aA);
        aB = fdot2f(xb[0], wh[0], aB); aB = fdot2f(xb[1], wh[1], aB);
        aB = fdot2f(xb[2], wh[2], aB); aB = fdot2f(xb[3], wh[3], aB);
    }
#pragma unroll
    for (int i = 0; i < 8; i++) {
        float4 xvA = *(const float4*)(XbA + 128 + i * 16);
        float4 xvB = *(const float4*)(XbB + 128 + i * 16);
        const h2f16* wh = (const h2f16*)&wb_[i];
        const h2f16* xa = (const h2f16*)&xvA;
        const h2f16* xb = (const h2f16*)&xvB;
        aA = fdot2f(xa[0], wh[0], aA); aA = fdot2f(xa[1], wh[1], aA);
        aA = fdot2f(xa[2], wh[2], aA); aA = fdot2f(xa[3], wh[3], aA);
        aB = fdot2f(xb[0], wh[0], aB); aB = fdot2f(xb[1], wh[1], aB);
        aB = fdot2f(xb[2], wh[2], aB); aB = fdot2f(xb[3], wh[3], aB);
    }
    return {aA, aB};
}

// f32 K-split GEMV for k_pre (original row-major f32 weights), dual x.
template <int NXT>
__device__ __forceinline__ void gemvf32d(const float* s_xn, float* wbuf,
                                         const char* nextG, int nrs, int w, int ln,
                                         float4& accA, float4& accB) {
    const float4* w4 = (const float4*)wbuf;
    float4 wr[16];
    wait_vm<8>();
#pragma unroll
    for (int r = 0; r < 8; r++) wr[r] = w4[r * 64 + ln];
    sbar0(); wait_lgkm0(); sbar0();
    if (NXT) { stage8f(nextG, nrs, (char*)wbuf, ln); wait_vm<8>(); }
    else     wait_vm<0>();
#pragma unroll
    for (int r = 8; r < 16; r++) wr[r] = w4[r * 64 + ln];
    sbar0(); wait_lgkm0(); sbar0();
    if (NXT) stage8f(nextG + (size_t)8 * nrs, nrs, (char*)wbuf + 8192, ln);
    accA = {0, 0, 0, 0}; accB = {0, 0, 0, 0};
#pragma unroll
    for (int r = 0; r < 16; r++) {
        float aA = s_xn[w * 16 + r], aB = s_xn[128 + w * 16 + r];
        accA.x += aA * wr[r].x; accA.y += aA * wr[r].y;
        accA.z += aA * wr[r].z; accA.w += aA * wr[r].w;
        accB.x += aB * wr[r].x; accB.y += aB * wr[r].y;
        accB.z += aB * wr[r].z; accB.w += aB * wr[r].w;
    }
}

// N-value block reduce (8 waves); results broadcast into vals[].
template <int N>
__device__ __forceinline__ void block_reduce_n(float* vals, float* sbuf) {
#pragma unroll
    for (int off = 32; off > 0; off >>= 1)
#pragma unroll
        for (int q = 0; q < N; q++) vals[q] += __shfl_xor(vals[q], off, 64);
    int wave = threadIdx.x >> 6;
    if ((threadIdx.x & 63) == 0)
#pragma unroll
        for (int q = 0; q < N; q++) sbuf[wave * N + q] = vals[q];
    __syncthreads();
#pragma unroll
    for (int q = 0; q < N; q++) {
        float r = 0.0f;
#pragma unroll
        for (int g = 0; g < 8; g++) r += sbuf[g * N + q];
        vals[q] = r;
    }
    __syncthreads();
}

__device__ __forceinline__ float gelu_exact(float a) {
    return 0.5f * a * (1.0f + erff(a * 0.70710678f));
}

// ---------- k_pre: cvt prologue + sedge precompute + dual-node QKV(0) ----------
__global__ __launch_bounds__(512, 1) void k_pre(
        const int* indices, const float* coords, const int* bonds, const float* noise,
        const float* atom_emb, const float* ln1_g, const float* ln1_b,
        const float* Wq, const float* bq, const float* Wkv, const float* bkv,
        const float* Wo, const float* W1, const float* W2,
        __half* hWq, __half* hWkv, __half* hWo, __half* hW1, __half* hW2,
        float* nodes, float* qb, __half* hk, __half* hv, float* sedgews,
        const float* blin, float* out) {
    int blk = blockIdx.x;
    int b = blk >> 6;
    int iA = blk & 63, iB = iA + 64;
    int bnA = b * 128 + iA, bnB = b * 128 + iB;
    int t  = threadIdx.x;
    int d  = t & 127;
    bool act = (t < 256);
    int nodesel = (t >> 7) & 1;                 // 0 = node A dims, 1 = node B dims
    int w = t >> 6, ln = t & 63;
    __shared__ float arena[32768];              // 8 waves x 16 KB f32 slices
    __shared__ float scoord[384];
    __shared__ int   sadjA[128];
    __shared__ int   sadjB[128];
    __shared__ float s_xn[256];                 // A dims [0,128), B dims [128,256)
    __shared__ float s_red[96];
    __shared__ float s_part[4096];              // A region [0,2048), B [2048,4096)
    float* wbuf = arena + w * 4096;
    char*  wbufc = (char*)wbuf;

    if (blk == 0 && t == 0) out[0] = 256.0f * blin[0];

    // f32 QKV phase table: {q lo, q hi, k lo, k hi, v lo, v hi}
    const char* phB[6] = {(const char*)Wq,            (const char*)Wq + 1024,
                          (const char*)Wkv,           (const char*)Wkv + 1024,
                          (const char*)Wkv + 2048,    (const char*)Wkv + 3072};
    const int phRS[6] = {2048, 2048, 4096, 4096, 4096, 4096};

    // stage phase 0 (A then B halves); lands during setup + cvt below
    stage8f(phB[0] + (size_t)(w * 16) * phRS[0], phRS[0], wbufc, ln);
    stage8f(phB[0] + (size_t)(w * 16 + 8) * phRS[0], phRS[0], wbufc + 8192, ln);

    // ---- one-time setup: coords, adjacency, masked edge rows for BOTH nodes ----
    if (t < 3 * NN) scoord[t] = coords[b * 3 * NN + t];
    if (t < NN) { sadjA[t] = 0; sadjB[t] = 0; }
    __syncthreads();
    if (t < EE) {
        int e0 = bonds[2 * t], e1 = bonds[2 * t + 1];
        if (e0 == iA) sadjA[e1] = 1;
        if (e1 == iA) sadjA[e0] = 1;
        if (e0 == iB) sadjB[e1] = 1;
        if (e1 == iB) sadjB[e0] = 1;
    }
    __syncthreads();
    if (t < NN) {
        int j = t;
        float mA = sadjA[j] ? 1.0f : 0.0f;
        float mB = sadjB[j] ? 1.0f : 0.0f;
        sedgews[bnA * 384 + 3 * j + 0] = mA * (scoord[3 * iA + 0] - scoord[3 * j + 0]);
        sedgews[bnA * 384 + 3 * j + 1] = mA * (scoord[3 * iA + 1] - scoord[3 * j + 1]);
        sedgews[bnA * 384 + 3 * j + 2] = mA * (scoord[3 * iA + 2] - scoord[3 * j + 2]);
        sedgews[bnB * 384 + 3 * j + 0] = mB * (scoord[3 * iB + 0] - scoord[3 * j + 0]);
        sedgews[bnB * 384 + 3 * j + 1] = mB * (scoord[3 * iB + 1] - scoord[3 * j + 1]);
        sedgews[bnB * 384 + 3 * j + 2] = mB * (scoord[3 * iB + 2] - scoord[3 * j + 2]);
    }

    // ---- gather + LN1(0), both nodes ----
    float nd = 0.0f;
    if (act) {
        int idx = indices[nodesel ? bnB : bnA];
        nd = (d < NF) ? atom_emb[idx * NF + d] : noise[0];
        nodes[(nodesel ? bnB : bnA) * DIMM + d] = nd;
    }
    {
        float vals[4] = {(act && !nodesel) ? nd : 0.0f, (act && !nodesel) ? nd * nd : 0.0f,
                         (act &&  nodesel) ? nd : 0.0f, (act &&  nodesel) ? nd * nd : 0.0f};
        block_reduce_n<4>(vals, s_red);
        float sm = nodesel ? vals[2] : vals[0];
        float sq = nodesel ? vals[3] : vals[1];
        float m   = sm * (1.0f / 128.0f);
        float var = sq * (1.0f / 128.0f) - m * m;
        if (act) s_xn[t] = (nd - m) * rsqrtf(var + 1e-5f) * ln1_g[d] + ln1_b[d];
    }

    // ---- cvt prologue: f32 -> chunked transposed f16 slabs (all 6 layers) ----
    for (int u = blk * 512 + t; u < 294912; u += NBLK * 512) {
        int s = u >> 13, within = u & 8191;
        int l = s / 6, m = s % 6;
        const float* src; __half* dst; int ncols, colofs, big;
        if (m == 0)      { src = Wq  + (size_t)l * 65536;  dst = hWq  + (size_t)l * 65536;         ncols = 512;  colofs = 0;   big = 0; }
        else if (m == 1) { src = Wkv + (size_t)l * 131072; dst = hWkv + (size_t)l * 131072;        ncols = 1024; colofs = 0;   big = 0; }
        else if (m == 2) { src = Wkv + (size_t)l * 131072; dst = hWkv + (size_t)l * 131072 + 65536;ncols = 1024; colofs = 512; big = 0; }
        else if (m == 3) { src = W1  + (size_t)l * 65536;  dst = hW1  + (size_t)l * 65536;         ncols = 512;  colofs = 0;   big = 0; }
        else if (m == 4) { src = Wo  + (size_t)l * 65536;  dst = hWo  + (size_t)l * 65536;         ncols = 128;  colofs = 0;   big = 1; }
        else             { src = W2  + (size_t)l * 65536;  dst = hW2  + (size_t)l * 65536;         ncols = 128;  colofs = 0;   big = 1; }
        int rb, col;
        if (!big) { rb = within >> 9; col = within & 511; }
        else      { rb = within >> 7; col = within & 127; }
        int row0 = rb * 8;
        __align__(16) __half tmp[8];
#pragma unroll
        for (int e = 0; e < 8; e++)
            tmp[e] = __float2half(src[(size_t)(row0 + e) * ncols + colofs + col]);
        int dh;
        if (!big) dh = (col >> 6) * 8192 + rb * 512 + (col & 63) * 8;
        else {
            int kq = row0 >> 7, ci = (row0 & 127) >> 3;
            dh = (col >> 4) * 8192 + ci * 512 + ((col & 15) * 4 + kq) * 8;
        }
        *(float4*)&dst[dh] = *(const float4*)tmp;
    }
    __syncthreads();

    // ---- QKV from f32 weights, 6 half-phases, dual node, rolling staging ----
#define PRE_COMBINE(P)                                                         \
    {                                                                          \
        ((float4*)(s_part + w * 256))[ln]        = accA;                       \
        ((float4*)(s_part + 2048 + w * 256))[ln] = accB;                       \
        __syncthreads();                                                       \
        {                                                                      \
            int nn = t >> 8, tc = t & 255;                                     \
            float sS = 0.0f;                                                   \
            _Pragma("unroll")                                                  \
            for (int g = 0; g < 8; g++) sS += s_part[nn * 2048 + g * 256 + tc];\
            int col = ((P) & 1) * 256 + tc;                                    \
            size_t bnX = nn ? (size_t)bnB : (size_t)bnA;                       \
            if ((P) < 2)      qb[bnX * INNER + col] = sS + bq[col];            \
            else if ((P) < 4) hk[bnX * INNER + col] =                          \
                                  __float2half(sS + bkv[col]);                 \
            else              hv[bnX * INNER + col] =                          \
                                  __float2half(sS + bkv[INNER + col]);         \
        }                                                                      \
        __syncthreads();                                                       \
    }

    {
        float4 accA, accB;
        gemvf32d<1>(s_xn, wbuf, phB[1] + (size_t)(w * 16) * phRS[1], phRS[1], w, ln, accA, accB);
        PRE_COMBINE(0);
        gemvf32d<1>(s_xn, wbuf, phB[2] + (size_t)(w * 16) * phRS[2], phRS[2], w, ln, accA, accB);
        PRE_COMBINE(1);
        gemvf32d<1>(s_xn, wbuf, phB[3] + (size_t)(w * 16) * phRS[3], phRS[3], w, ln, accA, accB);
        PRE_COMBINE(2);
        gemvf32d<1>(s_xn, wbuf, phB[4] + (size_t)(w * 16) * phRS[4], phRS[4], w, ln, accA, accB);
        PRE_COMBINE(3);
        gemvf32d<1>(s_xn, wbuf, phB[5] + (size_t)(w * 16) * phRS[5], phRS[5], w, ln, accA, accB);
        PRE_COMBINE(4);
        gemvf32d<0>(s_xn, wbuf, nullptr, 0, w, ln, accA, accB);
        PRE_COMBINE(5);
    }
#undef PRE_COMBINE
}

__global__ __launch_bounds__(512, 1) void k_layer(int l,
        const float* sedgews,
        const float* We, const float* be,
        float* qb, const __half* hkin, const __half* hvin,
        __half* hkout, __half* hvout,
        const __half* hWo, const float* bo, const float* Wg1,
        const float* ln2_g, const float* ln2_b,
        const __half* hW1, const float* b1,
        const __half* hW2, const float* b2,
        const float* Wg2,
        const float* ln1_g, const float* ln1_b,
        const __half* hWq, const float* bq,
        const __half* hWkv, const float* bkv,
        float* nodes, const float* Wlin, float* out) {
    int blk = blockIdx.x;
    int b = blk >> 6;
    int iA = blk & 63;
    int bnA = b * 128 + iA, bnB = bnA + 64;
    int t = threadIdx.x;
    int d = t & 127;
    bool act = (t < 256);
    int nodesel = (t >> 7) & 1;
    int w = t >> 6, ln = t & 63;

    __shared__ float arena[32768];     // 8 waves x 16 KB weight slices
    __shared__ float sedge[2][384];
    __shared__ float s_l[2][64];
    __shared__ __align__(16) __half s_aoh[2][544];   // kq-padded (4 x 136)
    __shared__ __align__(16) __half s_hh[2][544];
    __shared__ __align__(16) __half s_xh[256];       // A [0,128), B [128,256)
    __shared__ float s_x[256];
    __shared__ float s_red[96];
    __shared__ float s_part[4096];     // attention o-combine (2 rounds)
    float* s_o = s_part;
    float* wbuf = arena + w * 4096;

    const char* WoL  = (const char*)hWo + (size_t)l * 131072 + w * 16384;
    const char* W1L  = (const char*)hW1 + (size_t)l * 131072 + w * 16384;
    const char* W2L  = (const char*)hW2 + (size_t)l * 131072 + w * 16384;
    const char* WqnL = (const char*)hWq + (size_t)(l + 1) * 131072 + w * 16384;
    const char* WknL = (const char*)hWkv + (size_t)(l + 1) * 262144 + w * 16384;
    const char* WvnL = (const char*)hWkv + (size_t)(l + 1) * 262144 + 131072 + w * 16384;

    // stage Wo (A then B halves); lands during the attention phase
    stage8c(WoL, (char*)wbuf, ln);
    stage8c(WoL + 8192, (char*)wbuf + 8192, ln);

    // ---------- attention, dual node: wave w owns j in [w*16, w*16+16) ----------
    const float4* qR4A = (const float4*)(qb + (size_t)bnA * INNER);
    const float4* qR4B = (const float4*)(qb + (size_t)bnB * INNER);
    const float4* WeR  = (const float4*)(We + (size_t)l * 3 * INNER);
    float4 qaA = qR4A[ln * 2], qzA = qR4A[ln * 2 + 1];
    float4 qaB = qR4B[ln * 2], qzB = qR4B[ln * 2 + 1];
    float4 w0a = WeR[ln * 2],       w0z = WeR[ln * 2 + 1];
    float4 w1a = WeR[128 + ln * 2], w1z = WeR[129 + ln * 2];
    float4 w2a = WeR[256 + ln * 2], w2z = WeR[257 + ln * 2];
    float4 bea = ((const float4*)(be + (size_t)l * INNER))[ln * 2];
    float4 bez = ((const float4*)(be + (size_t)l * INNER))[ln * 2 + 1];
    float res = act ? nodes[(nodesel ? bnB : bnA) * DIMM + d] : 0.0f;
    h2f16 qhA0 = {(_Float16)qaA.x, (_Float16)qaA.y};
    h2f16 qhA1 = {(_Float16)qaA.z, (_Float16)qaA.w};
    h2f16 qhA2 = {(_Float16)qzA.x, (_Float16)qzA.y};
    h2f16 qhA3 = {(_Float16)qzA.z, (_Float16)qzA.w};
    h2f16 qhB0 = {(_Float16)qaB.x, (_Float16)qaB.y};
    h2f16 qhB1 = {(_Float16)qaB.z, (_Float16)qaB.w};
    h2f16 qhB2 = {(_Float16)qzB.x, (_Float16)qzB.y};
    h2f16 qhB3 = {(_Float16)qzB.z, (_Float16)qzB.w};
    // per-head q.be constants (non-bonded j have e == be exactly)
    float cA = qaA.x * bea.x + qaA.y * bea.y + qaA.z * bea.z + qaA.w * bea.w
             + qzA.x * bez.x + qzA.y * bez.y + qzA.z * bez.z + qzA.w * bez.w;
    float cB = qaB.x * bea.x + qaB.y * bea.y + qaB.z * bea.z + qaB.w * bea.w
             + qzB.x * bez.x + qzB.y * bez.y + qzB.z * bez.z + qzB.w * bez.w;
    cA += __shfl_xor(cA, 1, 64); cA += __shfl_xor(cA, 2, 64); cA += __shfl_xor(cA, 4, 64);
    cB += __shfl_xor(cB, 1, 64); cB += __shfl_xor(cB, 2, 64); cB += __shfl_xor(cB, 4, 64);

    if (t < 384) {
        sedge[0][t] = sedgews[bnA * 384 + t];
        sedge[1][t] = sedgews[bnB * 384 + t];
    }
    __syncthreads();

    const float4* kR = (const float4*)(hkin + (size_t)b * NN * INNER);   // 8 halves/elt
    const float4* vR = (const float4*)(hvin + (size_t)b * NN * INNER);
    float l_runA = 0.0f, S_nbA = 0.0f, l_runB = 0.0f, S_nbB = 0.0f;
    float4 o0A = {0,0,0,0}, o1A = {0,0,0,0}, o0B = {0,0,0,0}, o1B = {0,0,0,0};
    int j0 = w * 16;
#pragma unroll
    for (int base = 0; base < 16; base += 4) {
        float4 kraw[4], vraw[4];
#pragma unroll
        for (int p = 0; p < 4; p++) {
            int j = j0 + base + p;
            kraw[p] = kR[j * 64 + ln];
            vraw[p] = vR[j * 64 + ln];
        }
#pragma unroll
        for (int p = 0; p < 4; p++) {
            int j = j0 + base + p;
            const h2f16* kh = (const h2f16*)&kraw[p];
            float sA = fdot2f(qhA0, kh[0], fdot2f(qhA1, kh[1],
                       fdot2f(qhA2, kh[2], fdot2f(qhA3, kh[3], 0.0f))));
            float sB = fdot2f(qhB0, kh[0], fdot2f(qhB1, kh[1],
                       fdot2f(qhB2, kh[2], fdot2f(qhB3, kh[3], 0.0f))));
            float exA = sedge[0][3 * j], eyA = sedge[0][3 * j + 1], ezA = sedge[0][3 * j + 2];
            float exB = sedge[1][3 * j], eyB = sedge[1][3 * j + 1], ezB = sedge[1][3 * j + 2];
            bool bondedA = (exA != 0.0f) || (eyA != 0.0f) || (ezA != 0.0f);
            bool bondedB = (exB != 0.0f) || (eyB != 0.0f) || (ezB != 0.0f);
            float4 e0A, e1A, e0B, e1B;
            if (bondedA) {
                e0A.x = bea.x + exA * w0a.x + eyA * w1a.x + ezA * w2a.x;
                e0A.y = bea.y + exA * w0a.y + eyA * w1a.y + ezA * w2a.y;
                e0A.z = bea.z + exA * w0a.z + eyA * w1a.z + ezA * w2a.z;
                e0A.w = bea.w + exA * w0a.w + eyA * w1a.w + ezA * w2a.w;
                e1A.x = bez.x + exA * w0z.x + eyA * w1z.x + ezA * w2z.x;
                e1A.y = bez.y + exA * w0z.y + eyA * w1z.y + ezA * w2z.y;
                e1A.z = bez.z + exA * w0z.z + eyA * w1z.z + ezA * w2z.z;
                e1A.w = bez.w + exA * w0z.w + eyA * w1z.w + ezA * w2z.w;
                sA += qaA.x * e0A.x + qaA.y * e0A.y + qaA.z * e0A.z + qaA.w * e0A.w
                    + qzA.x * e1A.x + qzA.y * e1A.y + qzA.z * e1A.z + qzA.w * e1A.w;
            }
            if (bondedB) {
                e0B.x = bea.x + exB * w0a.x + eyB * w1a.x + ezB * w2a.x;
                e0B.y = bea.y + exB * w0a.y + eyB * w1a.y + ezB * w2a.y;
                e0B.z = bea.z + exB * w0a.z + eyB * w1a.z + ezB * w2a.z;
                e0B.w = bea.w + exB * w0a.w + eyB * w1a.w + ezB * w2a.w;
                e1B.x = bez.x + exB * w0z.x + eyB * w1z.x + ezB * w2z.x;
                e1B.y = bez.y + exB * w0z.y + eyB * w1z.y + ezB * w2z.y;
                e1B.z = bez.z + exB * w0z.z + eyB * w1z.z + ezB * w2z.z;
                e1B.w = bez.w + exB * w0z.w + eyB * w1z.w + ezB * w2z.w;
                sB += qaB.x * e0B.x + qaB.y * e0B.y + qaB.z * e0B.z + qaB.w * e0B.w
                    + qzB.x * e1B.x + qzB.y * e1B.y + qzB.z * e1B.z + qzB.w * e1B.w;
            }
            sA += __shfl_xor(sA, 1, 64); sA += __shfl_xor(sA, 2, 64); sA += __shfl_xor(sA, 4, 64);
            sB += __shfl_xor(sB, 1, 64); sB += __shfl_xor(sB, 2, 64); sB += __shfl_xor(sB, 4, 64);
            if (!bondedA) sA += cA;
            if (!bondedB) sB += cB;
            float ppA = __expf(sA * 0.125f);
            float ppB = __expf(sB * 0.125f);
            l_runA += ppA; l_runB += ppB;
            const __half2* vh = (const __half2*)&vraw[p];
            float2 v0 = __half22float2(vh[0]), v1 = __half22float2(vh[1]);
            float2 v2 = __half22float2(vh[2]), v3 = __half22float2(vh[3]);
            o0A.x += ppA * v0.x; o0A.y += ppA * v0.y; o0A.z += ppA * v1.x; o0A.w += ppA * v1.y;
            o1A.x += ppA * v2.x; o1A.y += ppA * v2.y; o1A.z += ppA * v3.x; o1A.w += ppA * v3.y;
            o0B.x += ppB * v0.x; o0B.y += ppB * v0.y; o0B.z += ppB * v1.x; o0B.w += ppB * v1.y;
            o1B.x += ppB * v2.x; o1B.y += ppB * v2.y; o1B.z += ppB * v3.x; o1B.w += ppB * v3.y;
            if (bondedA) {
                o0A.x += ppA * e0A.x; o0A.y += ppA * e0A.y; o0A.z += ppA * e0A.z; o0A.w += ppA * e0A.w;
                o1A.x += ppA * e1A.x; o1A.y += ppA * e1A.y; o1A.z += ppA * e1A.z; o1A.w += ppA * e1A.w;
            } else S_nbA += ppA;
            if (bondedB) {
                o0B.x += ppB * e0B.x; o0B.y += ppB * e0B.y; o0B.z += ppB * e0B.z; o0B.w += ppB * e0B.w;
                o1B.x += ppB * e1B.x; o1B.y += ppB * e1B.y; o1B.z += ppB * e1B.z; o1B.w += ppB * e1B.w;
            } else S_nbB += ppB;
        }
    }
    o0A.x += S_nbA * bea.x; o0A.y += S_nbA * bea.y; o0A.z += S_nbA * bea.z; o0A.w += S_nbA * bea.w;
    o1A.x += S_nbA * bez.x; o1A.y += S_nbA * bez.y; o1A.z += S_nbA * bez.z; o1A.w += S_nbA * bez.w;
    o0B.x += S_nbB * bea.x; o0B.y += S_nbB * bea.y; o0B.z += S_nbB * bea.z; o0B.w += S_nbB * bea.w;
    o1B.x += S_nbB * bez.x; o1B.y += S_nbB * bez.y; o1B.z += S_nbB * bez.z; o1B.w += S_nbB * bez.w;

    // two-round o-combine through s_part (16 KB)
    ((float4*)(s_o + w * 512))[ln * 2]     = o0A;
    ((float4*)(s_o + w * 512))[ln * 2 + 1] = o1A;
    if ((ln & 7) == 0) {
        s_l[0][w * 8 + (ln >> 3)] = l_runA;
        s_l[1][w * 8 + (ln >> 3)] = l_runB;
    }
    __syncthreads();
    float oaccA = 0.0f, lsumA = 0.0f;
    {
#pragma unroll
        for (int g = 0; g < 8; g++) oaccA += s_o[g * 512 + t];
        int h = t >> 6;
#pragma unroll
        for (int g = 0; g < 8; g++) lsumA += s_l[0][g * 8 + h];
    }
    __syncthreads();
    ((float4*)(s_o + w * 512))[ln * 2]     = o0B;
    ((float4*)(s_o + w * 512))[ln * 2 + 1] = o1B;
    __syncthreads();
    {
        float oaccB = 0.0f, lsumB = 0.0f;
#pragma unroll
        for (int g = 0; g < 8; g++) oaccB += s_o[g * 512 + t];
        int h = t >> 6;
#pragma unroll
        for (int g = 0; g < 8; g++) lsumB += s_l[1][g * 8 + h];
        int idx = (t >> 7) * 136 + (t & 127);
        s_aoh[0][idx] = __float2half(oaccA / lsumA);
        s_aoh[1][idx] = __float2half(oaccB / lsumB);
    }
    __syncthreads();

    // ---------- Wo [512 x 128], dual (stages W1 mid-phase) ----------
    {
        float2 xo = gemv128d<1>(s_aoh[0], s_aoh[1], wbuf, W1L, ln);
        xo.x += __shfl_xor(xo.x, 1, 64); xo.x += __shfl_xor(xo.x, 2, 64);
        xo.y += __shfl_xor(xo.y, 1, 64); xo.y += __shfl_xor(xo.y, 2, 64);
        if ((ln & 3) == 0) {
            s_x[w * 16 + (ln >> 2)]       = xo.x;
            s_x[128 + w * 16 + (ln >> 2)] = xo.y;
        }
    }
    __syncthreads();
    float x = act ? s_x[t] + bo[l * DIMM + d] : 0.0f;

    // ---------- fused gate1 + LN2, both nodes in one reduce ----------
    const float* Wg1_l = Wg1 + l * 3 * DIMM;
    float n1;
    {
        float tex = act ? (x * Wg1_l[d] + res * Wg1_l[DIMM + d]
                           + (x - res) * Wg1_l[2 * DIMM + d]) : 0.0f;
        float v6[6] = {tex, x, x * x, x * res, res, res * res};
        float vals[12];
#pragma unroll
        for (int q = 0; q < 6; q++) {
            vals[q]     = (act && !nodesel) ? v6[q] : 0.0f;
            vals[6 + q] = (act &&  nodesel) ? v6[q] : 0.0f;
        }
        block_reduce_n<12>(vals, s_red);
        const float* vv = vals + 6 * nodesel;
        float g1 = 1.0f / (1.0f + __expf(-vv[0]));
        float sn  = g1 * vv[1] + (1.0f - g1) * vv[4];
        float sn2 = g1 * g1 * vv[2] + 2.0f * g1 * (1.0f - g1) * vv[3]
                  + (1.0f - g1) * (1.0f - g1) * vv[5];
        float m   = sn * (1.0f / 128.0f);
        float var = sn2 * (1.0f / 128.0f) - m * m;
        n1 = x * g1 + res * (1.0f - g1);
        if (act) s_xh[t] = __float2half((n1 - m) * rsqrtf(var + 1e-5f) * ln2_g[l * DIMM + d]
                                        + ln2_b[l * DIMM + d]);
    }
    __syncthreads();

    // ---------- W1 [128 x 512] + gelu, dual (stages W2 mid-phase) ----------
    {
        float2 a1 = gemv512d<1>(s_xh, wbuf, W2L, ln);
        int col = w * 64 + ln;
        float bb = b1[l * 4 * DIMM + col];
        int idx = (col >> 7) * 136 + (col & 127);
        s_hh[0][idx] = __float2half(gelu_exact(a1.x + bb));
        s_hh[1][idx] = __float2half(gelu_exact(a1.y + bb));
    }
    __syncthreads();

    // ---------- W2 [512 x 128], dual (stages next-layer Wq if needed) ----------
    {
        float2 yw;
        if (l < DEPTH - 1) yw = gemv128d<1>(s_hh[0], s_hh[1], wbuf, WqnL, ln);
        else               yw = gemv128d<0>(s_hh[0], s_hh[1], wbuf, nullptr, ln);
        yw.x += __shfl_xor(yw.x, 1, 64); yw.x += __shfl_xor(yw.x, 2, 64);
        yw.y += __shfl_xor(yw.y, 1, 64); yw.y += __shfl_xor(yw.y, 2, 64);
        if ((ln & 3) == 0) {
            s_x[w * 16 + (ln >> 2)]       = yw.x;
            s_x[128 + w * 16 + (ln >> 2)] = yw.y;
        }
    }
    __syncthreads();
    float y = act ? s_x[t] + b2[l * DIMM + d] : 0.0f;

    const float* Wg2_l = Wg2 + l * 3 * DIMM;
    if (l < DEPTH - 1) {
        // ---------- fused gate2 + LN1', both nodes ----------
        float tex = act ? (y * Wg2_l[d] + n1 * Wg2_l[DIMM + d]
                           + (y - n1) * Wg2_l[2 * DIMM + d]) : 0.0f;
        float v6[6] = {tex, y, y * y, y * n1, n1, n1 * n1};
        float vals[12];
#pragma unroll
        for (int q = 0; q < 6; q++) {
            vals[q]     = (act && !nodesel) ? v6[q] : 0.0f;
            vals[6 + q] = (act &&  nodesel) ? v6[q] : 0.0f;
        }
        block_reduce_n<12>(vals, s_red);
        const float* vv = vals + 6 * nodesel;
        float g2 = 1.0f / (1.0f + __expf(-vv[0]));
        float sn  = g2 * vv[1] + (1.0f - g2) * vv[4];
        float sn2 = g2 * g2 * vv[2] + 2.0f * g2 * (1.0f - g2) * vv[3]
                  + (1.0f - g2) * (1.0f - g2) * vv[5];
        float m   = sn * (1.0f / 128.0f);
        float var = sn2 * (1.0f / 128.0f) - m * m;
        float n2 = y * g2 + n1 * (1.0f - g2);
        if (act) {
            nodes[(nodesel ? bnB : bnA) * DIMM + d] = n2;
            s_xh[t] = __float2half((n2 - m) * rsqrtf(var + 1e-5f) * ln1_g[(l + 1) * DIMM + d]
                                   + ln1_b[(l + 1) * DIMM + d]);
        }
        __syncthreads();

        int col = w * 64 + ln;
        // ---------- Wq' / Wk' / Wv' back-to-back, dual, zero barriers ----------
        {
            float2 q = gemv512d<1>(s_xh, wbuf, WknL, ln);
            float bb = bq[(l + 1) * INNER + col];
            qb[(size_t)bnA * INNER + col] = q.x + bb;
            qb[(size_t)bnB * INNER + col] = q.y + bb;
        }
        {
            float2 kk = gemv512d<1>(s_xh, wbuf, WvnL, ln);
            float bb = bkv[(l + 1) * 2 * INNER + col];
            hkout[(size_t)bnA * INNER + col] = __float2half(kk.x + bb);
            hkout[(size_t)bnB * INNER + col] = __float2half(kk.y + bb);
        }
        {
            float2 vv2 = gemv512d<0>(s_xh, wbuf, nullptr, ln);
            float bb = bkv[(l + 1) * 2 * INNER + INNER + col];
            hvout[(size_t)bnA * INNER + col] = __float2half(vv2.x + bb);
            hvout[(size_t)bnB * INNER + col] = __float2half(vv2.y + bb);
        }
    } else {
        // ---------- fused gate2 + final contribution, both nodes ----------
        float wl = act ? Wlin[d] : 0.0f;
        float tex = act ? (y * Wg2_l[d] + n1 * Wg2_l[DIMM + d]
                           + (y - n1) * Wg2_l[2 * DIMM + d]) : 0.0f;
        float v3[3] = {tex, y * wl, n1 * wl};
        float vals[6];
#pragma unroll
        for (int q = 0; q < 3; q++) {
            vals[q]     = (act && !nodesel) ? v3[q] : 0.0f;
            vals[3 + q] = (act &&  nodesel) ? v3[q] : 0.0f;
        }
        block_reduce_n<6>(vals, s_red);
        float g2A = 1.0f / (1.0f + __expf(-vals[0]));
        float g2B = 1.0f / (1.0f + __expf(-vals[3]));
        float tot = g2A * vals[1] + (1.0f - g2A) * vals[2]
                  + g2B * vals[4] + (1.0f - g2B) * vals[5];
        if (t == 0) atomicAdd(out, tot);
    }
}

extern "C" void kernel_launch(void* const* d_in, const int* in_sizes, int n_in,
                              void* d_out, int out_size, void* d_ws, size_t ws_size,
                              hipStream_t stream) {
    const int*   indices = (const int*)d_in[0];
    const float* coords  = (const float*)d_in[1];
    const int*   bonds   = (const int*)d_in[2];
    const float* noise   = (const float*)d_in[3];
    const float* atom_emb= (const float*)d_in[4];
    const float* ln1_g   = (const float*)d_in[5];
    const float* ln1_b   = (const float*)d_in[6];
    const float* Wq      = (const float*)d_in[7];
    const float* bq      = (const float*)d_in[8];
    const float* Wkv     = (const float*)d_in[9];
    const float* bkv     = (const float*)d_in[10];
    const float* We      = (const float*)d_in[11];
    const float* be      = (const float*)d_in[12];
    const float* Wo      = (const float*)d_in[13];
    const float* bo      = (const float*)d_in[14];
    const float* Wg1     = (const float*)d_in[15];
    const float* ln2_g   = (const float*)d_in[16];
    const float* ln2_b   = (const float*)d_in[17];
    const float* W1      = (const float*)d_in[18];
    const float* b1      = (const float*)d_in[19];
    const float* W2      = (const float*)d_in[20];
    const float* b2      = (const float*)d_in[21];
    const float* Wg2     = (const float*)d_in[22];
    const float* Wlin    = (const float*)d_in[23];
    const float* blin    = (const float*)d_in[24];

    float*  ws    = (float*)d_ws;
    float*  nodes = ws;                         // 32768 f
    float*  qb    = nodes + NNODE * DIMM;       // 131072 f
    __half* hkb   = (__half*)(qb + NNODE * INNER);  // 2 slabs x 131072 halves
    __half* hvb   = hkb + 2 * NNODE * INNER;
    __half* hWq   = hvb + 2 * NNODE * INNER;
    __half* hWkv  = hWq + DEPTH * DIMM * INNER;
    __half* hWo   = hWkv + DEPTH * DIMM * 2 * INNER;
    __half* hW1   = hWo + DEPTH * INNER * DIMM;
    __half* hW2   = hW1 + DEPTH * DIMM * 4 * DIMM;
    float*  sedgews = (float*)(hW2 + DEPTH * 4 * DIMM * DIMM);   // 256*384 f

    k_pre<<<NBLK, 512, 0, stream>>>(indices, coords, bonds, noise, atom_emb,
                                    ln1_g, ln1_b, Wq, bq, Wkv, bkv, Wo, W1, W2,
                                    hWq, hWkv, hWo, hW1, hW2,
                                    nodes, qb, hkb, hvb, sedgews, blin, (float*)d_out);
    for (int l = 0; l < DEPTH; l++) {
        const __half* hkin = hkb + (size_t)(l & 1) * NNODE * INNER;
        const __half* hvin = hvb + (size_t)(l & 1) * NNODE * INNER;
        __half* hkout = hkb + (size_t)((l + 1) & 1) * NNODE * INNER;
        __half* hvout = hvb + (size_t)((l + 1) & 1) * NNODE * INNER;
        k_layer<<<NBLK, 512, 0, stream>>>(l, sedgews, We, be,
                                          qb, hkin, hvin, hkout, hvout,
                                          hWo, bo, Wg1, ln2_g, ln2_b, hW1, b1, hW2, b2,
                                          Wg2, ln1_g, ln1_b, hWq, bq, hWkv, bkv,
                                          nodes, Wlin, (float*)d_out);
    }
}

// Round 7
// 228.924 us; speedup vs baseline: 1.2088x; 1.2088x over previous
//
#include <hip/hip_runtime.h>
#include <hip/hip_fp16.h>
#include <math.h>

#define DEPTH 6
#define NN    128
#define EE    160
#define NF    127
#define DIMM  128
#define INNER 512
#define NNODE 256

typedef _Float16 h2f16 __attribute__((ext_vector_type(2)));

#if defined(__has_builtin)
#if __has_builtin(__builtin_amdgcn_fdot2)
#define HAVE_FDOT2 1
#endif
#endif

__device__ __forceinline__ float fdot2f(h2f16 a, h2f16 b, float c) {
#ifdef HAVE_FDOT2
    return __builtin_amdgcn_fdot2(a, b, c, false);
#else
    return c + (float)a.x * (float)b.x + (float)a.y * (float)b.y;
#endif
}

// ---- direct-to-register weight access ----
// Chunked f16 slab layout (written by k_pre cvt prologue):
//   per-wave slice = 16 KB = 16 chunks x 1 KB; chunk i = K-rows [8i,8i+8) of
//   all 64 lane-columns; lane ln's 16 B at chunk + ln*16. A wave's load of one
//   chunk is a contiguous 1 KB (perfectly coalesced). No lane ever reads
//   another lane's bytes -> LDS staging would be pure overhead; registers only.
// Compiler tracks def-use of w[] and emits counted vmcnt waits itself.

__device__ __forceinline__ void ld8(float4 w[16], const char* g, int ln, int base) {
#pragma unroll
    for (int i = 0; i < 8; i++)
        w[base + i] = *(const float4*)(g + (size_t)(base + i) * 1024 + ln * 16);
}

__device__ __forceinline__ void dot8h(const float4 w[16], int base, const float4* X,
                                      float& a0, float& a1, float& a2, float& a3) {
#pragma unroll
    for (int i = 0; i < 8; i++) {
        float4 xv = X[base + i];
        const h2f16* wh = (const h2f16*)&w[base + i];
        const h2f16* xh = (const h2f16*)&xv;
        a0 = fdot2f(xh[0], wh[0], a0); a1 = fdot2f(xh[1], wh[1], a1);
        a2 = fdot2f(xh[2], wh[2], a2); a3 = fdot2f(xh[3], wh[3], a3);
    }
}

// C=512, K=128. Lane output col = w*64+ln; x = 128 halves broadcast from LDS.
// Consumes w (current matrix), refills w with nextG chunk-by-chunk mid-chain.
template <int NXT>
__device__ __forceinline__ float gemv512p(const __half* s_xh, float4 w[16],
                                          const char* nextG, int ln) {
    const float4* X = (const float4*)s_xh;
    float a0 = 0, a1 = 0, a2 = 0, a3 = 0;
    dot8h(w, 0, X, a0, a1, a2, a3);
    if (NXT) ld8(w, nextG, ln, 0);        // anti-dep: issues after w[0..7] consumed
    dot8h(w, 8, X, a0, a1, a2, a3);
    if (NXT) ld8(w, nextG, ln, 8);
    return (a0 + a1) + (a2 + a3);
}

// C=128, K=512. Lane: col = w*16+(ln>>2), kq = ln&3 owns rows kq*128+[0,128).
// x kq-padded: half idx = (row>>7)*136 + (row&127). Caller combines 4 partials
// with shfl_xor(1)+shfl_xor(2).
template <int NXT>
__device__ __forceinline__ float gemv128p(const __half* s_xp, float4 w[16],
                                          const char* nextG, int ln) {
    const float4* X = (const float4*)((const char*)s_xp + (ln & 3) * 272);
    float a0 = 0, a1 = 0, a2 = 0, a3 = 0;
    dot8h(w, 0, X, a0, a1, a2, a3);
    if (NXT) ld8(w, nextG, ln, 0);
    dot8h(w, 8, X, a0, a1, a2, a3);
    if (NXT) ld8(w, nextG, ln, 8);
    return (a0 + a1) + (a2 + a3);
}

// f32 K-split unit for k_pre (original row-major f32 weights).
// Wave w owns K-rows [w*16,+16) of a 256-col half; lane ln cols [ln*4,ln*4+4).
__device__ __forceinline__ void ldf8(float4 w[16], const char* g, int rs, int ln, int base) {
#pragma unroll
    for (int r = 0; r < 8; r++)
        w[base + r] = *(const float4*)(g + (size_t)(base + r) * rs + ln * 16);
}
template <int NXT>
__device__ __forceinline__ void gemvf32p(const float* s_xn, float4 w[16],
                                         const char* nextG, int nrs, int wv, int ln,
                                         float4& acc) {
    acc = {0, 0, 0, 0};
#pragma unroll
    for (int r = 0; r < 8; r++) {
        float a = s_xn[wv * 16 + r];
        acc.x += a * w[r].x; acc.y += a * w[r].y;
        acc.z += a * w[r].z; acc.w += a * w[r].w;
    }
    if (NXT) ldf8(w, nextG, nrs, ln, 0);
#pragma unroll
    for (int r = 8; r < 16; r++) {
        float a = s_xn[wv * 16 + r];
        acc.x += a * w[r].x; acc.y += a * w[r].y;
        acc.z += a * w[r].z; acc.w += a * w[r].w;
    }
    if (NXT) ldf8(w, nextG, nrs, ln, 8);
}

// N-value block reduce (8 waves); results broadcast into vals[].
template <int N>
__device__ __forceinline__ void block_reduce_n(float* vals, float* sbuf) {
#pragma unroll
    for (int off = 32; off > 0; off >>= 1)
#pragma unroll
        for (int q = 0; q < N; q++) vals[q] += __shfl_xor(vals[q], off, 64);
    int wave = threadIdx.x >> 6;
    if ((threadIdx.x & 63) == 0)
#pragma unroll
        for (int q = 0; q < N; q++) sbuf[wave * N + q] = vals[q];
    __syncthreads();
#pragma unroll
    for (int q = 0; q < N; q++) {
        float r = 0.0f;
#pragma unroll
        for (int g = 0; g < 8; g++) r += sbuf[g * N + q];
        vals[q] = r;
    }
    __syncthreads();
}

__device__ __forceinline__ float gelu_exact(float a) {
    return 0.5f * a * (1.0f + erff(a * 0.70710678f));
}

// ---------- k_pre: cvt prologue + sedge precompute + node QKV(0) ----------
__global__ __launch_bounds__(512, 1) void k_pre(
        const int* indices, const float* coords, const int* bonds, const float* noise,
        const float* atom_emb, const float* ln1_g, const float* ln1_b,
        const float* Wq, const float* bq, const float* Wkv, const float* bkv,
        const float* Wo, const float* W1, const float* W2,
        __half* hWq, __half* hWkv, __half* hWo, __half* hW1, __half* hW2,
        float* nodes, float* qb, __half* hk, __half* hv, float* sedgews,
        const float* blin, float* out) {
    int bn = blockIdx.x;
    int b = bn >> 7, i = bn & 127;
    int t  = threadIdx.x;
    int d  = t & 127;
    bool own = (t < 128);
    int w = t >> 6, ln = t & 63;
    __shared__ float scoord[384];
    __shared__ int   sadj[128];
    __shared__ float s_xn[128];
    __shared__ float s_red[48];
    __shared__ float s_part[2048];
    __shared__ float lds_pad[24576];   // force 1 block/CU (LDS > 80 KB)
    if (out == (float*)1) lds_pad[t] = 0.0f;   // never true; keeps pad allocated

    if (bn == 0 && t == 0) out[0] = 256.0f * blin[0];

    // f32 QKV phase table: {q lo, q hi, k lo, k hi, v lo, v hi}
    const char* phB[6] = {(const char*)Wq,            (const char*)Wq + 1024,
                          (const char*)Wkv,           (const char*)Wkv + 1024,
                          (const char*)Wkv + 2048,    (const char*)Wkv + 3072};
    const int phRS[6] = {2048, 2048, 4096, 4096, 4096, 4096};

    // ---- one-time setup: coords, adjacency, masked edge row -> ws ----
    if (t < 3 * NN) scoord[t] = coords[b * 3 * NN + t];
    if (t < NN) sadj[t] = 0;
    __syncthreads();
    if (t < EE) {
        int e0 = bonds[2 * t], e1 = bonds[2 * t + 1];
        if (e0 == i) sadj[e1] = 1;
        if (e1 == i) sadj[e0] = 1;
    }
    __syncthreads();
    if (t < NN) {
        int j = t;
        float msk = sadj[j] ? 1.0f : 0.0f;
        sedgews[bn * 384 + 3 * j + 0] = msk * (scoord[3 * i + 0] - scoord[3 * j + 0]);
        sedgews[bn * 384 + 3 * j + 1] = msk * (scoord[3 * i + 1] - scoord[3 * j + 1]);
        sedgews[bn * 384 + 3 * j + 2] = msk * (scoord[3 * i + 2] - scoord[3 * j + 2]);
    }

    // ---- gather + LN1(0) ----
    float nd = 0.0f;
    if (own) {
        int idx = indices[bn];
        nd = (d < NF) ? atom_emb[idx * NF + d] : noise[0];
        nodes[bn * DIMM + d] = nd;
    }
    {
        float vals[2] = {own ? nd : 0.0f, own ? nd * nd : 0.0f};
        block_reduce_n<2>(vals, s_red);
        float m   = vals[0] * (1.0f / 128.0f);
        float var = vals[1] * (1.0f / 128.0f) - m * m;
        if (own) s_xn[d] = (nd - m) * rsqrtf(var + 1e-5f) * ln1_g[d] + ln1_b[d];
    }

    // ---- cvt prologue: f32 -> chunked transposed f16 slabs (all 6 layers) ----
    for (int u = bn * 512 + t; u < 294912; u += NNODE * 512) {
        int s = u >> 13, within = u & 8191;
        int l = s / 6, m = s % 6;
        const float* src; __half* dst; int ncols, colofs, big;
        if (m == 0)      { src = Wq  + (size_t)l * 65536;  dst = hWq  + (size_t)l * 65536;         ncols = 512;  colofs = 0;   big = 0; }
        else if (m == 1) { src = Wkv + (size_t)l * 131072; dst = hWkv + (size_t)l * 131072;        ncols = 1024; colofs = 0;   big = 0; }
        else if (m == 2) { src = Wkv + (size_t)l * 131072; dst = hWkv + (size_t)l * 131072 + 65536;ncols = 1024; colofs = 512; big = 0; }
        else if (m == 3) { src = W1  + (size_t)l * 65536;  dst = hW1  + (size_t)l * 65536;         ncols = 512;  colofs = 0;   big = 0; }
        else if (m == 4) { src = Wo  + (size_t)l * 65536;  dst = hWo  + (size_t)l * 65536;         ncols = 128;  colofs = 0;   big = 1; }
        else             { src = W2  + (size_t)l * 65536;  dst = hW2  + (size_t)l * 65536;         ncols = 128;  colofs = 0;   big = 1; }
        int rb, col;
        if (!big) { rb = within >> 9; col = within & 511; }
        else      { rb = within >> 7; col = within & 127; }
        int row0 = rb * 8;
        __align__(16) __half tmp[8];
#pragma unroll
        for (int e = 0; e < 8; e++)
            tmp[e] = __float2half(src[(size_t)(row0 + e) * ncols + colofs + col]);
        int dh;
        if (!big) dh = (col >> 6) * 8192 + rb * 512 + (col & 63) * 8;
        else {
            int kq = row0 >> 7, ci = (row0 & 127) >> 3;
            dh = (col >> 4) * 8192 + ci * 512 + ((col & 15) * 4 + kq) * 8;
        }
        *(float4*)&dst[dh] = *(const float4*)tmp;
    }

    // issue phase-0 weight loads; latency hides under the barrier + combine
    float4 wr[16];
    ldf8(wr, phB[0] + (size_t)(w * 16) * phRS[0], phRS[0], ln, 0);
    ldf8(wr, phB[0] + (size_t)(w * 16) * phRS[0], phRS[0], ln, 8);
    __syncthreads();

    // ---- QKV from f32 weights, 6 half-phases, rolling register window ----
#define PRE_COMBINE(P)                                                        \
    {                                                                         \
        ((float4*)(s_part + w * 256))[ln] = acc;                              \
        __syncthreads();                                                      \
        if (t < 256) {                                                        \
            float sS = 0.0f;                                                  \
            _Pragma("unroll")                                                 \
            for (int g = 0; g < 8; g++) sS += s_part[g * 256 + t];            \
            int col = ((P) & 1) * 256 + t;                                    \
            if ((P) < 2)      qb[(size_t)bn * INNER + col] = sS + bq[col];    \
            else if ((P) < 4) hk[(size_t)bn * INNER + col] =                  \
                                  __float2half(sS + bkv[col]);                \
            else              hv[(size_t)bn * INNER + col] =                  \
                                  __float2half(sS + bkv[INNER + col]);        \
        }                                                                     \
        __syncthreads();                                                      \
    }

    {
        float4 acc;
        gemvf32p<1>(s_xn, wr, phB[1] + (size_t)(w * 16) * phRS[1], phRS[1], w, ln, acc);
        PRE_COMBINE(0);
        gemvf32p<1>(s_xn, wr, phB[2] + (size_t)(w * 16) * phRS[2], phRS[2], w, ln, acc);
        PRE_COMBINE(1);
        gemvf32p<1>(s_xn, wr, phB[3] + (size_t)(w * 16) * phRS[3], phRS[3], w, ln, acc);
        PRE_COMBINE(2);
        gemvf32p<1>(s_xn, wr, phB[4] + (size_t)(w * 16) * phRS[4], phRS[4], w, ln, acc);
        PRE_COMBINE(3);
        gemvf32p<1>(s_xn, wr, phB[5] + (size_t)(w * 16) * phRS[5], phRS[5], w, ln, acc);
        PRE_COMBINE(4);
        gemvf32p<0>(s_xn, wr, nullptr, 0, w, ln, acc);
        PRE_COMBINE(5);
    }
#undef PRE_COMBINE
}

__global__ __launch_bounds__(512, 1) void k_layer(int l,
        const float* sedgews,
        const float* We, const float* be,
        float* qb, const __half* hkin, const __half* hvin,
        __half* hkout, __half* hvout,
        const __half* hWo, const float* bo, const float* Wg1,
        const float* ln2_g, const float* ln2_b,
        const __half* hW1, const float* b1,
        const __half* hW2, const float* b2,
        const float* Wg2,
        const float* ln1_g, const float* ln1_b,
        const __half* hWq, const float* bq,
        const __half* hWkv, const float* bkv,
        float* nodes, const float* Wlin, float* out) {
    int bn = blockIdx.x;
    int b = bn >> 7;
    int t = threadIdx.x;
    int d = t & 127;
    bool own = (t < 128);
    int w = t >> 6, ln = t & 63;

    __shared__ float sedge[384];
    __shared__ float s_l[64];
    __shared__ __align__(16) __half s_aoh[544];   // kq-padded (4 x 136)
    __shared__ __align__(16) __half s_hh[544];    // kq-padded
    __shared__ __align__(16) __half s_xh[128];
    __shared__ float s_x[128];
    __shared__ float s_red[48];
    __shared__ float s_part[4096];     // attention o-combine only
    __shared__ float lds_pad[24576];   // force 1 block/CU (LDS > 80 KB)
    if (out == (float*)1) lds_pad[t] = 0.0f;
    float* s_o = s_part;

    const char* WoL  = (const char*)hWo + (size_t)l * 131072 + w * 16384;
    const char* W1L  = (const char*)hW1 + (size_t)l * 131072 + w * 16384;
    const char* W2L  = (const char*)hW2 + (size_t)l * 131072 + w * 16384;
    const char* WqnL = (const char*)hWq + (size_t)(l + 1) * 131072 + w * 16384;
    const char* WknL = (const char*)hWkv + (size_t)(l + 1) * 262144 + w * 16384;
    const char* WvnL = (const char*)hWkv + (size_t)(l + 1) * 262144 + 131072 + w * 16384;

    // ---------- attention: wave w owns j in [w*16, w*16+16); 64 lanes = 512 dims ----------
    const float4* qR4 = (const float4*)(qb + (size_t)bn * INNER);
    const float4* WeR = (const float4*)(We + (size_t)l * 3 * INNER);
    float4 qa  = qR4[ln * 2],        qz  = qR4[ln * 2 + 1];
    float4 w0a = WeR[ln * 2],        w0z = WeR[ln * 2 + 1];
    float4 w1a = WeR[128 + ln * 2],  w1z = WeR[129 + ln * 2];
    float4 w2a = WeR[256 + ln * 2],  w2z = WeR[257 + ln * 2];
    float4 bea = ((const float4*)(be + (size_t)l * INNER))[ln * 2];
    float4 bez = ((const float4*)(be + (size_t)l * INNER))[ln * 2 + 1];
    float res = own ? nodes[bn * DIMM + d] : 0.0f;
    h2f16 qh0 = {(_Float16)qa.x, (_Float16)qa.y};
    h2f16 qh1 = {(_Float16)qa.z, (_Float16)qa.w};
    h2f16 qh2 = {(_Float16)qz.x, (_Float16)qz.y};
    h2f16 qh3 = {(_Float16)qz.z, (_Float16)qz.w};
    // per-head q.be (non-bonded j have e == be exactly)
    float c = qa.x * bea.x + qa.y * bea.y + qa.z * bea.z + qa.w * bea.w
            + qz.x * bez.x + qz.y * bez.y + qz.z * bez.z + qz.w * bez.w;
    c += __shfl_xor(c, 1, 64); c += __shfl_xor(c, 2, 64); c += __shfl_xor(c, 4, 64);

    if (t < 384) sedge[t] = sedgews[bn * 384 + t];
    __syncthreads();

    const float4* kR = (const float4*)(hkin + (size_t)b * NN * INNER);   // 8 halves/elt
    const float4* vR = (const float4*)(hvin + (size_t)b * NN * INNER);
    float l_run = 0.0f, S_nb = 0.0f;
    float4 o0 = {0, 0, 0, 0}, o1 = {0, 0, 0, 0};
    int j0 = w * 16;
#pragma unroll
    for (int base = 0; base < 16; base += 4) {
        float4 kraw[4], vraw[4];
#pragma unroll
        for (int p = 0; p < 4; p++) {
            int j = j0 + base + p;
            kraw[p] = kR[j * 64 + ln];
            vraw[p] = vR[j * 64 + ln];
        }
#pragma unroll
        for (int p = 0; p < 4; p++) {
            int j = j0 + base + p;
            const h2f16* kh = (const h2f16*)&kraw[p];
            float s = fdot2f(qh0, kh[0],
                      fdot2f(qh1, kh[1],
                      fdot2f(qh2, kh[2],
                      fdot2f(qh3, kh[3], 0.0f))));
            float ex = sedge[3 * j], ey = sedge[3 * j + 1], ez = sedge[3 * j + 2];
            bool bonded = (ex != 0.0f) || (ey != 0.0f) || (ez != 0.0f);  // wave-uniform
            float4 e0, e1;
            if (bonded) {
                e0.x = bea.x + ex * w0a.x + ey * w1a.x + ez * w2a.x;
                e0.y = bea.y + ex * w0a.y + ey * w1a.y + ez * w2a.y;
                e0.z = bea.z + ex * w0a.z + ey * w1a.z + ez * w2a.z;
                e0.w = bea.w + ex * w0a.w + ey * w1a.w + ez * w2a.w;
                e1.x = bez.x + ex * w0z.x + ey * w1z.x + ez * w2z.x;
                e1.y = bez.y + ex * w0z.y + ey * w1z.y + ez * w2z.y;
                e1.z = bez.z + ex * w0z.z + ey * w1z.z + ez * w2z.z;
                e1.w = bez.w + ex * w0z.w + ey * w1z.w + ez * w2z.w;
                s += qa.x * e0.x + qa.y * e0.y + qa.z * e0.z + qa.w * e0.w
                   + qz.x * e1.x + qz.y * e1.y + qz.z * e1.z + qz.w * e1.w;
            }
            s += __shfl_xor(s, 1, 64);
            s += __shfl_xor(s, 2, 64);
            s += __shfl_xor(s, 4, 64);
            if (!bonded) s += c;
            float pp = __expf(s * 0.125f);
            l_run += pp;
            const __half2* vh = (const __half2*)&vraw[p];
            float2 v0 = __half22float2(vh[0]), v1 = __half22float2(vh[1]);
            float2 v2 = __half22float2(vh[2]), v3 = __half22float2(vh[3]);
            o0.x += pp * v0.x; o0.y += pp * v0.y; o0.z += pp * v1.x; o0.w += pp * v1.y;
            o1.x += pp * v2.x; o1.y += pp * v2.y; o1.z += pp * v3.x; o1.w += pp * v3.y;
            if (bonded) {
                o0.x += pp * e0.x; o0.y += pp * e0.y; o0.z += pp * e0.z; o0.w += pp * e0.w;
                o1.x += pp * e1.x; o1.y += pp * e1.y; o1.z += pp * e1.z; o1.w += pp * e1.w;
            } else S_nb += pp;
        }
    }
    // fold the shared be contribution of all non-bonded j
    o0.x += S_nb * bea.x; o0.y += S_nb * bea.y; o0.z += S_nb * bea.z; o0.w += S_nb * bea.w;
    o1.x += S_nb * bez.x; o1.y += S_nb * bez.y; o1.z += S_nb * bez.z; o1.w += S_nb * bez.w;

    // issue Wo loads now; latency hides under o-combine barriers below
    float4 wreg[16];
    ld8(wreg, WoL, ln, 0);
    ld8(wreg, WoL, ln, 8);

    ((float4*)(s_o + w * 512))[ln * 2]     = o0;
    ((float4*)(s_o + w * 512))[ln * 2 + 1] = o1;
    if ((ln & 7) == 0) s_l[w * 8 + (ln >> 3)] = l_run;
    __syncthreads();
    {
        float o = 0.0f;
#pragma unroll
        for (int g = 0; g < 8; g++) o += s_o[g * 512 + t];
        int h = t >> 6;
        float lsum = 0.0f;
#pragma unroll
        for (int g = 0; g < 8; g++) lsum += s_l[g * 8 + h];
        s_aoh[(t >> 7) * 136 + (t & 127)] = __float2half(o / lsum);
    }
    __syncthreads();

    // ---------- Wo [512 x 128] (loads W1 mid-chain) ----------
    {
        float xo = gemv128p<1>(s_aoh, wreg, W1L, ln);
        xo += __shfl_xor(xo, 1, 64);
        xo += __shfl_xor(xo, 2, 64);
        if ((ln & 3) == 0) s_x[w * 16 + (ln >> 2)] = xo;
    }
    __syncthreads();
    float x = own ? s_x[d] + bo[l * DIMM + d] : 0.0f;

    // ---------- fused gate1 + LN2 (single reduce pass) ----------
    const float* Wg1_l = Wg1 + l * 3 * DIMM;
    float n1;
    {
        float tex = own ? (x * Wg1_l[d] + res * Wg1_l[DIMM + d]
                           + (x - res) * Wg1_l[2 * DIMM + d]) : 0.0f;
        float vals[6] = {tex,
                         own ? x : 0.0f, own ? x * x : 0.0f,
                         own ? x * res : 0.0f,
                         own ? res : 0.0f, own ? res * res : 0.0f};
        block_reduce_n<6>(vals, s_red);
        float g1 = 1.0f / (1.0f + __expf(-vals[0]));
        float sn  = g1 * vals[1] + (1.0f - g1) * vals[4];
        float sn2 = g1 * g1 * vals[2] + 2.0f * g1 * (1.0f - g1) * vals[3]
                  + (1.0f - g1) * (1.0f - g1) * vals[5];
        float m   = sn * (1.0f / 128.0f);
        float var = sn2 * (1.0f / 128.0f) - m * m;
        n1 = x * g1 + res * (1.0f - g1);
        if (own) s_xh[d] = __float2half((n1 - m) * rsqrtf(var + 1e-5f) * ln2_g[l * DIMM + d]
                                        + ln2_b[l * DIMM + d]);
    }
    __syncthreads();

    // ---------- W1 [128 x 512] + gelu (loads W2 mid-chain) ----------
    {
        float a1 = gemv512p<1>(s_xh, wreg, W2L, ln);
        int col = w * 64 + ln;
        float ag = gelu_exact(a1 + b1[l * 4 * DIMM + col]);
        s_hh[(col >> 7) * 136 + (col & 127)] = __float2half(ag);
    }
    __syncthreads();

    // ---------- W2 [512 x 128] (loads next-layer Wq if needed) ----------
    {
        float yw;
        if (l < DEPTH - 1) yw = gemv128p<1>(s_hh, wreg, WqnL, ln);
        else               yw = gemv128p<0>(s_hh, wreg, nullptr, ln);
        yw += __shfl_xor(yw, 1, 64);
        yw += __shfl_xor(yw, 2, 64);
        if ((ln & 3) == 0) s_x[w * 16 + (ln >> 2)] = yw;
    }
    __syncthreads();
    float y = own ? s_x[d] + b2[l * DIMM + d] : 0.0f;

    const float* Wg2_l = Wg2 + l * 3 * DIMM;
    if (l < DEPTH - 1) {
        // ---------- fused gate2 + LN1' (single reduce pass) ----------
        float tex = own ? (y * Wg2_l[d] + n1 * Wg2_l[DIMM + d]
                           + (y - n1) * Wg2_l[2 * DIMM + d]) : 0.0f;
        float vals[6] = {tex,
                         own ? y : 0.0f, own ? y * y : 0.0f,
                         own ? y * n1 : 0.0f,
                         own ? n1 : 0.0f, own ? n1 * n1 : 0.0f};
        block_reduce_n<6>(vals, s_red);
        float g2 = 1.0f / (1.0f + __expf(-vals[0]));
        float sn  = g2 * vals[1] + (1.0f - g2) * vals[4];
        float sn2 = g2 * g2 * vals[2] + 2.0f * g2 * (1.0f - g2) * vals[3]
                  + (1.0f - g2) * (1.0f - g2) * vals[5];
        float m   = sn * (1.0f / 128.0f);
        float var = sn2 * (1.0f / 128.0f) - m * m;
        float n2 = y * g2 + n1 * (1.0f - g2);
        if (own) {
            nodes[bn * DIMM + d] = n2;
            s_xh[d] = __float2half((n2 - m) * rsqrtf(var + 1e-5f) * ln1_g[(l + 1) * DIMM + d]
                                   + ln1_b[(l + 1) * DIMM + d]);
        }
        __syncthreads();

        int col = w * 64 + ln;
        // ---------- Wq' / Wk' / Wv' back-to-back, zero barriers ----------
        {
            float q = gemv512p<1>(s_xh, wreg, WknL, ln);
            qb[(size_t)bn * INNER + col] = q + bq[(l + 1) * INNER + col];
        }
        {
            float kk = gemv512p<1>(s_xh, wreg, WvnL, ln);
            hkout[(size_t)bn * INNER + col] =
                __float2half(kk + bkv[(l + 1) * 2 * INNER + col]);
        }
        {
            float vv = gemv512p<0>(s_xh, wreg, nullptr, ln);
            hvout[(size_t)bn * INNER + col] =
                __float2half(vv + bkv[(l + 1) * 2 * INNER + INNER + col]);
        }
    } else {
        // ---------- fused gate2 + final contribution ----------
        float wl = own ? Wlin[d] : 0.0f;
        float tex = own ? (y * Wg2_l[d] + n1 * Wg2_l[DIMM + d]
                           + (y - n1) * Wg2_l[2 * DIMM + d]) : 0.0f;
        float vals[3] = {tex, y * wl, n1 * wl};
        block_reduce_n<3>(vals, s_red);
        float g2 = 1.0f / (1.0f + __expf(-vals[0]));
        float tot = g2 * vals[1] + (1.0f - g2) * vals[2];
        if (t == 0) atomicAdd(out, tot);
    }
}

extern "C" void kernel_launch(void* const* d_in, const int* in_sizes, int n_in,
                              void* d_out, int out_size, void* d_ws, size_t ws_size,
                              hipStream_t stream) {
    const int*   indices = (const int*)d_in[0];
    const float* coords  = (const float*)d_in[1];
    const int*   bonds   = (const int*)d_in[2];
    const float* noise   = (const float*)d_in[3];
    const float* atom_emb= (const float*)d_in[4];
    const float* ln1_g   = (const float*)d_in[5];
    const float* ln1_b   = (const float*)d_in[6];
    const float* Wq      = (const float*)d_in[7];
    const float* bq      = (const float*)d_in[8];
    const float* Wkv     = (const float*)d_in[9];
    const float* bkv     = (const float*)d_in[10];
    const float* We      = (const float*)d_in[11];
    const float* be      = (const float*)d_in[12];
    const float* Wo      = (const float*)d_in[13];
    const float* bo      = (const float*)d_in[14];
    const float* Wg1     = (const float*)d_in[15];
    const float* ln2_g   = (const float*)d_in[16];
    const float* ln2_b   = (const float*)d_in[17];
    const float* W1      = (const float*)d_in[18];
    const float* b1      = (const float*)d_in[19];
    const float* W2      = (const float*)d_in[20];
    const float* b2      = (const float*)d_in[21];
    const float* Wg2     = (const float*)d_in[22];
    const float* Wlin    = (const float*)d_in[23];
    const float* blin    = (const float*)d_in[24];

    float*  ws    = (float*)d_ws;
    float*  nodes = ws;                         // 32768 f
    float*  qb    = nodes + NNODE * DIMM;       // 131072 f
    __half* hkb   = (__half*)(qb + NNODE * INNER);  // 2 slabs x 131072 halves
    __half* hvb   = hkb + 2 * NNODE * INNER;
    __half* hWq   = hvb + 2 * NNODE * INNER;
    __half* hWkv  = hWq + DEPTH * DIMM * INNER;
    __half* hWo   = hWkv + DEPTH * DIMM * 2 * INNER;
    __half* hW1   = hWo + DEPTH * INNER * DIMM;
    __half* hW2   = hW1 + DEPTH * DIMM * 4 * DIMM;
    float*  sedgews = (float*)(hW2 + DEPTH * 4 * DIMM * DIMM);   // 256*384 f

    k_pre<<<NNODE, 512, 0, stream>>>(indices, coords, bonds, noise, atom_emb,
                                     ln1_g, ln1_b, Wq, bq, Wkv, bkv, Wo, W1, W2,
                                     hWq, hWkv, hWo, hW1, hW2,
                                     nodes, qb, hkb, hvb, sedgews, blin, (float*)d_out);
    for (int l = 0; l < DEPTH; l++) {
        const __half* hkin = hkb + (size_t)(l & 1) * NNODE * INNER;
        const __half* hvin = hvb + (size_t)(l & 1) * NNODE * INNER;
        __half* hkout = hkb + (size_t)((l + 1) & 1) * NNODE * INNER;
        __half* hvout = hvb + (size_t)((l + 1) & 1) * NNODE * INNER;
        k_layer<<<NNODE, 512, 0, stream>>>(l, sedgews, We, be,
                                           qb, hkin, hvin, hkout, hvout,
                                           hWo, bo, Wg1, ln2_g, ln2_b, hW1, b1, hW2, b2,
                                           Wg2, ln1_g, ln1_b, hWq, bq, hWkv, bkv,
                                           nodes, Wlin, (float*)d_out);
    }
}